// Round 1
// baseline (103.036 us; speedup 1.0000x reference)
//
#include <hip/hip_runtime.h>

// SoftFAPELoss: B=8, N=M=4096, D=3. Exact two-pass shifted softmax.
// This revision: packed-FP32 (v_pk_fma_f32) main loop. Q staged in LDS as
// pair-interleaved records {x0,x1,y0,y1}{z0,z1,w0,w1} so two ds_read_b128
// per q-pair alias directly onto packed operands (consecutive VGPRs).
// Pass 1: 3 pk_fma + 1 min3 per 2 pairs. Pass 2: 3 pk_fma + 1 pk_sub +
// 2 exp + 1 pk_add + 1 pk_fma per 2 pairs. A recomputed with identical
// packed expression in both passes -> sh - A <= 0 exact.

typedef float v2f __attribute__((ext_vector_type(2)));
typedef float v4f __attribute__((ext_vector_type(4)));

#define B_    8
#define N_    4096
#define M_    4096
#define NWAVE 8
#define BLOCK (NWAVE * 64)        // 512
#define ROWS  256                 // rows per block (4 per lane)
#define MSPL  8                   // M split across blocks
#define QCH   (M_ / MSPL)         // 512 q per block
#define WQ    (QCH / NWAVE)       // 64 q per wave (32 pairs)
#define LOG2E 1.4426950408889634f
#define LN2   0.6931471805599453f
#define BIGF  3.0e38f

__global__ __launch_bounds__(BLOCK, 4) void softfape_main(
    const float* __restrict__ X_pred, const float* __restrict__ X_true,
    const float* __restrict__ R_pred, const float* __restrict__ t_pred,
    const float* __restrict__ R_true, const float* __restrict__ t_true,
    const float* __restrict__ temp,
    float4* __restrict__ Pg)
{
    __shared__ v4f   Q[QCH];             // 8 KB, pair-interleaved records
    __shared__ float Mp[NWAVE][ROWS];    // 8 KB
    __shared__ float Lp[NWAVE][ROWS];    // 8 KB
    __shared__ float Sp[NWAVE][ROWS];    // 8 KB
    __shared__ float shl[ROWS];          // 1 KB (uniform shift per row)
    __shared__ float pwl[ROWS];          // 1 KB (c*|p|^2 per row)

    const int tid  = threadIdx.x;
    const int wave = tid >> 6;
    const int lane = tid & 63;
    const int x    = blockIdx.x;
    const int ms   = x & 7;
    const int rg   = (x >> 3) & 15;
    const int b    = x >> 7;

    const float T   = temp[0];
    const float c   = LOG2E / T;
    const float m2c = -2.0f * c;

    // ---- stage 512 transformed+prescaled q's as pair records (threads 0..255) ----
    if (tid < QCH / 2) {
        const float g00 = R_true[b*9+0], g01 = R_true[b*9+1], g02 = R_true[b*9+2];
        const float g10 = R_true[b*9+3], g11 = R_true[b*9+4], g12 = R_true[b*9+5];
        const float g20 = R_true[b*9+6], g21 = R_true[b*9+7], g22 = R_true[b*9+8];
        const float u0  = t_true[b*3+0], u1 = t_true[b*3+1], u2 = t_true[b*3+2];
        const float2* xt = (const float2*)(X_true + ((size_t)b * M_ + ms * QCH) * 3);
        const float2 f0 = xt[3*tid+0], f1 = xt[3*tid+1], f2 = xt[3*tid+2];
        // q0 = q(2*tid)
        const float a0 = fmaf(g00, f0.x, fmaf(g01, f0.y, fmaf(g02, f1.x, u0)));
        const float a1 = fmaf(g10, f0.x, fmaf(g11, f0.y, fmaf(g12, f1.x, u1)));
        const float a2 = fmaf(g20, f0.x, fmaf(g21, f0.y, fmaf(g22, f1.x, u2)));
        const float an = fmaf(a0, a0, fmaf(a1, a1, a2 * a2));
        // q1 = q(2*tid+1)
        const float b0 = fmaf(g00, f1.y, fmaf(g01, f2.x, fmaf(g02, f2.y, u0)));
        const float b1 = fmaf(g10, f1.y, fmaf(g11, f2.x, fmaf(g12, f2.y, u1)));
        const float b2 = fmaf(g20, f1.y, fmaf(g21, f2.x, fmaf(g22, f2.y, u2)));
        const float bn = fmaf(b0, b0, fmaf(b1, b1, b2 * b2));
        Q[2*tid]   = (v4f){m2c*a0, m2c*b0, m2c*a1, m2c*b1};   // {x0,x1,y0,y1}
        Q[2*tid+1] = (v4f){m2c*a2, m2c*b2, c*an,   c*bn  };   // {z0,z1,w0,w1}
    }

    // ---- my 4 rows: transformed pred points, pw = c*|p|^2; splat for pk ops ----
    v2f Px[4], Py[4], Pz[4];
    {
        const float h00 = R_pred[b*9+0], h01 = R_pred[b*9+1], h02 = R_pred[b*9+2];
        const float h10 = R_pred[b*9+3], h11 = R_pred[b*9+4], h12 = R_pred[b*9+5];
        const float h20 = R_pred[b*9+6], h21 = R_pred[b*9+7], h22 = R_pred[b*9+8];
        const float v0 = t_pred[b*3+0], v1 = t_pred[b*3+1], v2 = t_pred[b*3+2];
        const float4* xp = (const float4*)(X_pred + ((size_t)b * N_ + rg * ROWS + lane * 4) * 3);
        const float4 a0 = xp[0], a1 = xp[1], a2 = xp[2];
        const float rx[4] = {a0.x, a0.w, a1.z, a2.y};
        const float ry[4] = {a0.y, a1.x, a1.w, a2.z};
        const float rz[4] = {a0.z, a1.y, a2.x, a2.w};
        #pragma unroll
        for (int r = 0; r < 4; ++r) {
            const float px = fmaf(h00, rx[r], fmaf(h01, ry[r], fmaf(h02, rz[r], v0)));
            const float py = fmaf(h10, rx[r], fmaf(h11, ry[r], fmaf(h12, rz[r], v1)));
            const float pz = fmaf(h20, rx[r], fmaf(h21, ry[r], fmaf(h22, rz[r], v2)));
            const float pw = c * fmaf(px, px, fmaf(py, py, pz * pz));
            pwl[4*lane + r] = pw;   // rows are block-redundant across waves; same value
            Px[r] = (v2f){px, px};
            Py[r] = (v2f){py, py};
            Pz[r] = (v2f){pz, pz};
        }
    }

    __syncthreads();

    const v4f* __restrict__ Qw = Q + wave * WQ;   // 64 v4f records = 32 q-pairs

    // ---- pass 1: min of A over my 64-q slice (3 pk_fma + 1 min3 per 2 pairs) ----
    float mA[4] = {BIGF, BIGF, BIGF, BIGF};
    #pragma unroll 8
    for (int k = 0; k < WQ/2; ++k) {
        const v4f qa = Qw[2*k];       // ds_read_b128, wave-uniform broadcast
        const v4f qb = Qw[2*k+1];
        const v2f X2 = __builtin_shufflevector(qa, qa, 0, 1);
        const v2f Y2 = __builtin_shufflevector(qa, qa, 2, 3);
        const v2f Z2 = __builtin_shufflevector(qb, qb, 0, 1);
        const v2f W2 = __builtin_shufflevector(qb, qb, 2, 3);
        #pragma unroll
        for (int r = 0; r < 4; ++r) {
            const v2f A2 = __builtin_elementwise_fma(X2, Px[r],
                           __builtin_elementwise_fma(Y2, Py[r],
                           __builtin_elementwise_fma(Z2, Pz[r], W2)));
            mA[r] = fminf(mA[r], fminf(A2.x, A2.y));   // -> v_min3_f32
        }
    }
    #pragma unroll
    for (int r = 0; r < 4; ++r) Mp[wave][4*lane + r] = mA[r];
    __syncthreads();

    // ---- block-uniform per-row shift ----
    if (tid < ROWS) {
        float m = Mp[0][tid];
        #pragma unroll
        for (int w2 = 1; w2 < NWAVE; ++w2) m = fminf(m, Mp[w2][tid]);
        shl[tid] = m;
    }
    __syncthreads();

    const float4 sh4 = *(const float4*)&shl[4*lane];
    const float shs[4] = {sh4.x, sh4.y, sh4.z, sh4.w};
    v2f Sh[4];
    #pragma unroll
    for (int r = 0; r < 4; ++r) Sh[r] = (v2f){shs[r], shs[r]};

    // ---- pass 2: shifted sums, packed (3 pk_fma + pk_sub + 2 exp + pk_add + pk_fma) ----
    v2f L2[4], S2[4];
    #pragma unroll
    for (int r = 0; r < 4; ++r) { L2[r] = (v2f){0.f, 0.f}; S2[r] = (v2f){0.f, 0.f}; }
    #pragma unroll 8
    for (int k = 0; k < WQ/2; ++k) {
        const v4f qa = Qw[2*k];
        const v4f qb = Qw[2*k+1];
        const v2f X2 = __builtin_shufflevector(qa, qa, 0, 1);
        const v2f Y2 = __builtin_shufflevector(qa, qa, 2, 3);
        const v2f Z2 = __builtin_shufflevector(qb, qb, 0, 1);
        const v2f W2 = __builtin_shufflevector(qb, qb, 2, 3);
        #pragma unroll
        for (int r = 0; r < 4; ++r) {
            const v2f A2  = __builtin_elementwise_fma(X2, Px[r],
                            __builtin_elementwise_fma(Y2, Py[r],
                            __builtin_elementwise_fma(Z2, Pz[r], W2)));
            const v2f arg = Sh[r] - A2;                       // <= 0, pk_add(neg)
            const v2f w2  = {__builtin_amdgcn_exp2f(arg.x),
                             __builtin_amdgcn_exp2f(arg.y)};
            L2[r] += w2;                                      // pk_add
            S2[r]  = __builtin_elementwise_fma(w2, arg, S2[r]); // pk_fma
        }
    }
    #pragma unroll
    for (int r = 0; r < 4; ++r) {
        Lp[wave][4*lane + r] = L2[r].x + L2[r].y;
        Sp[wave][4*lane + r] = S2[r].x + S2[r].y;
    }
    __syncthreads();

    // ---- merge 8 wave-partials per row (same shift -> plain adds) ----
    if (tid < ROWS) {
        float Lr = 0.0f, Sr = 0.0f;
        #pragma unroll
        for (int w2 = 0; w2 < NWAVE; ++w2) { Lr += Lp[w2][tid]; Sr += Sp[w2][tid]; }
        const size_t row = (size_t)b * N_ + rg * ROWS + tid;
        // m_d = chunk-min of d = minA + pw (d-units); L = sum exp2(m_d - d);
        // SA = sum w*(m_d - d)
        Pg[row * MSPL + ms] = make_float4(shl[tid] + pwl[tid], Lr, Sr, 0.0f);
    }
}

__global__ __launch_bounds__(256) void softfape_finalize(
    const float4* __restrict__ Pg, const float* __restrict__ temp,
    float* __restrict__ out)
{
    __shared__ float ws4[4];
    const int tid = threadIdx.x;
    const size_t row = (size_t)blockIdx.x * 256 + tid;

    float4 P[MSPL];
    #pragma unroll
    for (int i = 0; i < MSPL; ++i) P[i] = Pg[row * MSPL + i];

    float m = P[0].x;
    #pragma unroll
    for (int i = 1; i < MSPL; ++i) m = fminf(m, P[i].x);

    float L = 0.0f, SA = 0.0f;
    #pragma unroll
    for (int i = 0; i < MSPL; ++i) {
        const float dm = m - P[i].x;                    // <= 0
        const float f  = __builtin_amdgcn_exp2f(dm);    // global-min chunk -> 1
        L  = fmaf(P[i].y, f, L);
        SA = fmaf(f, fmaf(dm, P[i].y, P[i].z), SA);
    }
    float wd = m - SA / L;   // = c * weighted_distance(row); L >= 1 guaranteed

    wd += __shfl_xor(wd, 1);  wd += __shfl_xor(wd, 2);  wd += __shfl_xor(wd, 4);
    wd += __shfl_xor(wd, 8);  wd += __shfl_xor(wd, 16); wd += __shfl_xor(wd, 32);
    if ((tid & 63) == 0) ws4[tid >> 6] = wd;
    __syncthreads();
    if (tid == 0) {
        const float s = ws4[0] + ws4[1] + ws4[2] + ws4[3];
        const float scale = temp[0] * LN2 / ((float)B_ * (float)N_);  // 1/c, mean
        atomicAdd(out, s * scale);
    }
}

extern "C" void kernel_launch(void* const* d_in, const int* in_sizes, int n_in,
                              void* d_out, int out_size, void* d_ws, size_t ws_size,
                              hipStream_t stream) {
    const float* X_pred = (const float*)d_in[0];
    const float* X_true = (const float*)d_in[1];
    const float* R_pred = (const float*)d_in[2];
    const float* t_pred = (const float*)d_in[3];
    const float* R_true = (const float*)d_in[4];
    const float* t_true = (const float*)d_in[5];
    const float* temp   = (const float*)d_in[6];
    float* out = (float*)d_out;

    float4* Pg = (float4*)d_ws;   // B*N*MSPL float4 = 4 MB, fully overwritten

    hipMemsetAsync(out, 0, sizeof(float), stream);

    softfape_main<<<dim3(B_ * 16 * MSPL), BLOCK, 0, stream>>>(
        X_pred, X_true, R_pred, t_pred, R_true, t_true, temp, Pg);

    softfape_finalize<<<dim3((B_ * N_) / 256), 256, 0, stream>>>(Pg, temp, out);
}